// Round 10
// baseline (322.530 us; speedup 1.0000x reference)
//
#include <hip/hip_runtime.h>

typedef unsigned short u16;
typedef unsigned int u32;
typedef __attribute__((ext_vector_type(4))) float floatx4;
typedef __attribute__((ext_vector_type(8))) __bf16 bf16x8;

#define MFMA_BF16(a, b, c) __builtin_amdgcn_mfma_f32_16x16x32_bf16((a), (b), (c), 0, 0, 0)

typedef const __attribute__((address_space(1))) void* gas_ptr;
typedef __attribute__((address_space(3))) void* las_ptr;

__device__ __forceinline__ void gll16(const void* g, void* l) {
  __builtin_amdgcn_global_load_lds((gas_ptr)g, (las_ptr)l, 16, 0, 0);
}

__device__ __forceinline__ u16 f2bf(float x) {
  u32 u = __builtin_bit_cast(u32, x);
  u = (u + 0x7fffu + ((u >> 16) & 1u)) >> 16;
  return (u16)u;
}

// ---------------------------------------------------------------------------
// Kernel 1: down/up vectors from palette.
// ---------------------------------------------------------------------------
__global__ void prep_downup(const float* __restrict__ pal,
                            const float* __restrict__ qd, const float* __restrict__ qu,
                            const float* __restrict__ kd, const float* __restrict__ ku,
                            const float* __restrict__ vd, const float* __restrict__ vu,
                            const float* __restrict__ od, const float* __restrict__ ou,
                            float* __restrict__ down_f, float* __restrict__ up_f) {
  int tid = blockIdx.x * blockDim.x + threadIdx.x;
  int w = tid / 10240;
  int rem = tid - w * 10240;
  const float* dsrc = (w == 0) ? qd : (w == 1) ? kd : (w == 2) ? vd : od;
  const float* usrc = (w == 0) ? qu : (w == 1) ? ku : (w == 2) ? vu : ou;
  bool isdown = rem < 5120;
  int row = isdown ? rem : rem - 5120;
  const float* src = (isdown ? dsrc : usrc) + row * 15;
  float s = 0.f;
#pragma unroll
  for (int p = 0; p < 15; ++p) s += pal[p] * src[p];
  if (isdown) down_f[w * 5120 + row] = s;
  else        up_f[w * 5120 + row] = s;
}

// ---------------------------------------------------------------------------
// Kernel 2: W_eff[n][k] = W[n][k] + sum_r up[n][r]*down[r][k], cast to bf16.
// ---------------------------------------------------------------------------
__global__ void build_weff(const float* __restrict__ Wq, const float* __restrict__ Wk,
                           const float* __restrict__ Wv, const float* __restrict__ Wo,
                           const float* __restrict__ down_f, const float* __restrict__ up_f,
                           u16* __restrict__ weff_qkv, u16* __restrict__ weff_o) {
  int tid = blockIdx.x * blockDim.x + threadIdx.x;  // 4 * 1638400
  int w = tid / 1638400;
  int rem = tid - w * 1638400;
  int n = rem / 1280;
  int k = rem - n * 1280;
  const float* W = (w == 0) ? Wq : (w == 1) ? Wk : (w == 2) ? Wv : Wo;
  const float* up = up_f + w * 5120 + n * 4;
  const float* dn = down_f + w * 5120 + k;
  float v = W[rem] + up[0] * dn[0] + up[1] * dn[1280] + up[2] * dn[2560] + up[3] * dn[3840];
  u16 hv = f2bf(v);
  if (w < 3) weff_qkv[w * 1638400 + rem] = hv;
  else       weff_o[rem] = hv;
}

// ---------------------------------------------------------------------------
// Kernel 3: x fp32 -> bf16
// ---------------------------------------------------------------------------
__global__ void cvt_x(const float4* __restrict__ x, ushort4* __restrict__ xb) {
  int i = blockIdx.x * blockDim.x + threadIdx.x;  // 1310720
  float4 v = x[i];
  ushort4 o;
  o.x = f2bf(v.x); o.y = f2bf(v.y); o.z = f2bf(v.z); o.w = f2bf(v.w);
  xb[i] = o;
}

// ---------------------------------------------------------------------------
// m97-style bf16 GEMM (QKV): C[M,N] = A[M,K] @ B[N,K]^T.  128x128, BK=32.
// Epilogue writes ALL of q/k/v natural + coalesced (the v transpose-scatter
// was the suspected hidden cost: 5.2M lane-scattered 2B stores).
// ---------------------------------------------------------------------------
__global__ __launch_bounds__(256) void gemm128_qkv(const u16* __restrict__ A, const u16* __restrict__ Bm,
                                                   u16* __restrict__ qb, u16* __restrict__ kb,
                                                   u16* __restrict__ vbuf, int K) {
  __shared__ __align__(16) u16 lA[128 * 32];
  __shared__ __align__(16) u16 lB[128 * 32];
  const int t = threadIdx.x;
  const int lane = t & 63;
  const int l15 = lane & 15, quad = lane >> 4;
  const int wid = t >> 6;
  const int wm = (wid >> 1) * 64;
  const int wn = (wid & 1) * 64;
  const int bm = blockIdx.x * 128;
  const int bn = blockIdx.y * 128;
  floatx4 acc[4][4] = {};

  const int r0 = t >> 2;
  const int r1 = (t >> 2) + 64;
  const int kc = t & 3;
  const u16* Ab = A + (long)bm * K;
  const u16* Bb = Bm + (long)bn * K;
  const int nkt = K >> 5;

  for (int kt = 0; kt < nkt; ++kt) {
    __syncthreads();
    const int k0 = kt * 32 + kc * 8;
    gll16(Ab + (long)r0 * K + k0, lA + t * 8);
    gll16(Ab + (long)r1 * K + k0, lA + (t + 256) * 8);
    gll16(Bb + (long)r0 * K + k0, lB + t * 8);
    gll16(Bb + (long)r1 * K + k0, lB + (t + 256) * 8);
    __syncthreads();
    bf16x8 af[4], bfr[4];
#pragma unroll
    for (int i = 0; i < 4; ++i)
      af[i] = *(const bf16x8*)(lA + (wm + i * 16 + l15) * 32 + quad * 8);
#pragma unroll
    for (int i = 0; i < 4; ++i)
      bfr[i] = *(const bf16x8*)(lB + (wn + i * 16 + l15) * 32 + quad * 8);
#pragma unroll
    for (int i = 0; i < 4; ++i)
#pragma unroll
      for (int j = 0; j < 4; ++j)
        acc[i][j] = MFMA_BF16(af[i], bfr[j], acc[i][j]);
  }

#pragma unroll
  for (int i = 0; i < 4; ++i) {
#pragma unroll
    for (int j = 0; j < 4; ++j) {
#pragma unroll
      for (int r = 0; r < 4; ++r) {
        int m = bm + wm + i * 16 + quad * 4 + r;
        int n = bn + wn + j * 16 + l15;
        u16 hv = f2bf(acc[i][j][r]);
        if (n < 1280) {
          qb[(long)m * 1280 + n] = hv;
        } else if (n < 2560) {
          kb[(long)m * 1280 + (n - 1280)] = hv;
        } else {
          vbuf[(long)m * 1280 + (n - 2560)] = hv;  // natural, coalesced
        }
      }
    }
  }
}

// ---------------------------------------------------------------------------
// V transpose (foolproof scalar version): vbuf[(b*2048+s)][n] ->
// vtb[(b*1280+n)*2048 + s].  64x64 tiles, 256 thr.  ALL accesses scalar u16;
// coalescing from lane-consecutiveness (phase 1: lane = n -> 128B contiguous
// global reads + conflict-free LDS writes; phase 2: lane = s -> 128B
// contiguous global writes).  tile stride 65 breaks transpose-read conflicts.
// Identity: dst[n*2048+s] = tile[s*65+n] = src[s*1280+n].
// ---------------------------------------------------------------------------
__global__ __launch_bounds__(256) void vtrans(const u16* __restrict__ vbuf,
                                              u16* __restrict__ vtb) {
  __shared__ u16 tile[64 * 65];
  const int t = threadIdx.x;
  const int sb = blockIdx.x * 64, nb = blockIdx.y * 64, b = blockIdx.z;
  const u16* src = vbuf + ((long)(b * 2048 + sb)) * 1280 + nb;
#pragma unroll
  for (int it = 0; it < 16; ++it) {
    int idx = t + it * 256;
    int s = idx >> 6, n = idx & 63;
    tile[s * 65 + n] = src[(long)s * 1280 + n];
  }
  __syncthreads();
  u16* dst = vtb + ((long)(b * 1280 + nb)) * 2048 + sb;
#pragma unroll
  for (int it = 0; it < 16; ++it) {
    int idx = t + it * 256;
    int n = idx >> 6, s = idx & 63;
    dst[(long)n * 2048 + s] = tile[s * 65 + n];
  }
}

// ---------------------------------------------------------------------------
// O-proj GEMM: 64x128 tile, grid 64x10 = 640 blocks.  fp32 out + bias.
// ---------------------------------------------------------------------------
__global__ __launch_bounds__(256) void gemm64_o(const u16* __restrict__ A, const u16* __restrict__ Bm,
                                                float* __restrict__ outf,
                                                const float* __restrict__ bias, int K) {
  __shared__ __align__(16) u16 lA[64 * 32];
  __shared__ __align__(16) u16 lB[128 * 32];
  const int t = threadIdx.x;
  const int lane = t & 63;
  const int l15 = lane & 15, quad = lane >> 4;
  const int wid = t >> 6;
  const int bm = blockIdx.x * 64;
  const int bn = blockIdx.y * 128;
  floatx4 acc[4][2] = {};

  const int r0 = t >> 2;
  const int r1 = (t >> 2) + 64;
  const int kc = t & 3;
  const u16* Ab = A + (long)bm * K;
  const u16* Bb = Bm + (long)bn * K;
  const int nkt = K >> 5;

  for (int kt = 0; kt < nkt; ++kt) {
    __syncthreads();
    const int k0 = kt * 32 + kc * 8;
    gll16(Ab + (long)r0 * K + k0, lA + t * 8);
    gll16(Bb + (long)r0 * K + k0, lB + t * 8);
    gll16(Bb + (long)r1 * K + k0, lB + (t + 256) * 8);
    __syncthreads();
    bf16x8 af[4], bfr[2];
#pragma unroll
    for (int i = 0; i < 4; ++i)
      af[i] = *(const bf16x8*)(lA + (i * 16 + l15) * 32 + quad * 8);
#pragma unroll
    for (int j = 0; j < 2; ++j)
      bfr[j] = *(const bf16x8*)(lB + (wid * 32 + j * 16 + l15) * 32 + quad * 8);
#pragma unroll
    for (int i = 0; i < 4; ++i)
#pragma unroll
      for (int j = 0; j < 2; ++j)
        acc[i][j] = MFMA_BF16(af[i], bfr[j], acc[i][j]);
  }

#pragma unroll
  for (int i = 0; i < 4; ++i) {
#pragma unroll
    for (int j = 0; j < 2; ++j) {
#pragma unroll
      for (int r = 0; r < 4; ++r) {
        int m = bm + i * 16 + quad * 4 + r;
        int n = bn + wid * 32 + j * 16 + l15;
        outf[(long)m * 1280 + n] = acc[i][j][r] + bias[n];
      }
    }
  }
}

// ---------------------------------------------------------------------------
// Flash attention v3 (best measured: ~101 µs).  Grid (S/64, B*H), 256 thr =
// 4 waves, 16 q-rows/wave.  LDS-staged K/V via global_load_lds with swizzled
// slot maps; fixed-base softmax (no max, log2 domain, clamp 80); P round-trip
// per-wave LDS stride 76.
// ---------------------------------------------------------------------------
__global__ __launch_bounds__(256) void flash_attn(const u16* __restrict__ qb,
                                                  const u16* __restrict__ kb,
                                                  const u16* __restrict__ vtb,
                                                  u16* __restrict__ attn) {
  const int S = 2048, D = 1280, HD = 160;
  __shared__ __align__(16) u16 kt_lds[64 * 160];
  __shared__ __align__(16) u16 vt_lds[160 * 64];
  __shared__ __align__(16) u16 p_lds[4][16 * 76];
  const int t = threadIdx.x, lane = t & 63, wid = t >> 6;
  const int quad = lane >> 4, l15 = lane & 15;
  const int bh = blockIdx.y, b = bh >> 3, h = bh & 7;
  const int q0 = blockIdx.x * 64 + wid * 16;
  const float kS = 0.11404582025f;

  bf16x8 aq[5];
  {
    const u16* qg = qb + ((long)(b * 2048 + q0 + l15)) * D + h * HD + quad * 8;
#pragma unroll
    for (int dc = 0; dc < 5; ++dc) aq[dc] = *(const bf16x8*)(qg + dc * 32);
  }

  const u16* kg[5];
  const u16* vg[5];
  {
    const u16* kgbase = kb + ((long)(b * 2048)) * D + h * HD;
    const u16* vgbase = vtb + ((long)(b * 1280 + h * HD)) * 2048;
#pragma unroll
    for (int i = 0; i < 5; ++i) {
      int c = t + i * 256;
      int key = c / 20, rot = c - key * 20;
      int ccol = rot - (key % 20);
      if (ccol < 0) ccol += 20;
      kg[i] = kgbase + (long)key * D + ccol * 8;
      int vrow = c >> 3, swz = c & 7;
      int vcol = swz ^ (vrow & 7);
      vg[i] = vgbase + (long)vrow * 2048 + vcol * 8;
    }
  }

  int kfo[4][5];
#pragma unroll
  for (int j = 0; j < 4; ++j) {
    int key = j * 16 + l15;
    int r0 = (quad + key) % 20;
#pragma unroll
    for (int dc = 0; dc < 5; ++dc) {
      int rot = r0 + dc * 4;
      if (rot >= 20) rot -= 20;
      kfo[j][dc] = (key * 20 + rot) * 8;
    }
  }
  int vfo[10][2];
#pragma unroll
  for (int dc = 0; dc < 10; ++dc) {
    int row = dc * 16 + l15;
#pragma unroll
    for (int ks = 0; ks < 2; ++ks) {
      int sw = (ks * 4 + quad) ^ (row & 7);
      vfo[dc][ks] = (row * 8 + sw) * 8;
    }
  }

  float l_part[4] = {0.f, 0.f, 0.f, 0.f};
  floatx4 o_acc[10] = {};

  for (int kt0 = 0; kt0 < S; kt0 += 64) {
    __syncthreads();
#pragma unroll
    for (int i = 0; i < 5; ++i) gll16(kg[i], kt_lds + (t + i * 256) * 8);
#pragma unroll
    for (int i = 0; i < 5; ++i) gll16(vg[i], vt_lds + (t + i * 256) * 8);
#pragma unroll
    for (int i = 0; i < 5; ++i) { kg[i] += (long)64 * D; vg[i] += 64; }
    __syncthreads();

    floatx4 s[4] = {};
#pragma unroll
    for (int dc = 0; dc < 5; ++dc) {
#pragma unroll
      for (int j = 0; j < 4; ++j) {
        bf16x8 kf = *(const bf16x8*)(kt_lds + kfo[j][dc]);
        s[j] = MFMA_BF16(aq[dc], kf, s[j]);
      }
    }

#pragma unroll
    for (int r = 0; r < 4; ++r) {
      float p0 = __builtin_exp2f(fminf(s[0][r] * kS, 80.f));
      float p1 = __builtin_exp2f(fminf(s[1][r] * kS, 80.f));
      float p2 = __builtin_exp2f(fminf(s[2][r] * kS, 80.f));
      float p3 = __builtin_exp2f(fminf(s[3][r] * kS, 80.f));
      l_part[r] += (p0 + p1) + (p2 + p3);
      u16* pw = p_lds[wid] + (quad * 4 + r) * 76 + l15;
      pw[0]  = f2bf(p0);
      pw[16] = f2bf(p1);
      pw[32] = f2bf(p2);
      pw[48] = f2bf(p3);
    }
    asm volatile("s_waitcnt lgkmcnt(0)" ::: "memory");

    bf16x8 paA = *(const bf16x8*)(p_lds[wid] + l15 * 76 + quad * 8);
    bf16x8 paB = *(const bf16x8*)(p_lds[wid] + l15 * 76 + 32 + quad * 8);
#pragma unroll
    for (int dc = 0; dc < 10; ++dc) {
      bf16x8 vfA = *(const bf16x8*)(vt_lds + vfo[dc][0]);
      bf16x8 vfB = *(const bf16x8*)(vt_lds + vfo[dc][1]);
      o_acc[dc] = MFMA_BF16(paA, vfA, o_acc[dc]);
      o_acc[dc] = MFMA_BF16(paB, vfB, o_acc[dc]);
    }
  }

  float rl[4];
#pragma unroll
  for (int r = 0; r < 4; ++r) {
    float rs = l_part[r];
    rs += __shfl_xor(rs, 1, 64);
    rs += __shfl_xor(rs, 2, 64);
    rs += __shfl_xor(rs, 4, 64);
    rs += __shfl_xor(rs, 8, 64);
    rl[r] = 1.0f / rs;
  }
#pragma unroll
  for (int dc = 0; dc < 10; ++dc) {
#pragma unroll
    for (int r = 0; r < 4; ++r) {
      float v = o_acc[dc][r] * rl[r];
      int row = q0 + quad * 4 + r;
      int col = h * HD + dc * 16 + l15;
      attn[((long)(b * 2048 + row)) * D + col] = f2bf(v);
    }
  }
}

// ---------------------------------------------------------------------------
// Launcher.  Workspace (~76.2 MB; harness ws >= 108 MB verified in R6):
//   xb @0 | weff_qkv @10485760 | weff_o @20316160 | qbuf @23592960
//   kbuf @34078720 | vtb @44564480 | attn @55050240 | down_f @65536000
//   up_f @65617920 | vbuf @65699840 (10485760)
// ---------------------------------------------------------------------------
extern "C" void kernel_launch(void* const* d_in, const int* in_sizes, int n_in,
                              void* d_out, int out_size, void* d_ws, size_t ws_size,
                              hipStream_t stream) {
  const float* x   = (const float*)d_in[0];
  const float* pal = (const float*)d_in[1];
  const float* Wq  = (const float*)d_in[2];
  const float* Wk  = (const float*)d_in[3];
  const float* Wv  = (const float*)d_in[4];
  const float* Wo  = (const float*)d_in[5];
  const float* bo  = (const float*)d_in[6];
  const float* qd  = (const float*)d_in[7];
  const float* qu  = (const float*)d_in[8];
  const float* kd  = (const float*)d_in[9];
  const float* ku  = (const float*)d_in[10];
  const float* vd  = (const float*)d_in[11];
  const float* vu  = (const float*)d_in[12];
  const float* od  = (const float*)d_in[13];
  const float* ou  = (const float*)d_in[14];
  float* out = (float*)d_out;

  char* ws = (char*)d_ws;
  u16* xb       = (u16*)(ws);
  u16* weff_qkv = (u16*)(ws + 10485760);
  u16* weff_o   = (u16*)(ws + 20316160);
  u16* qbuf     = (u16*)(ws + 23592960);
  u16* kbuf     = (u16*)(ws + 34078720);
  u16* vtb      = (u16*)(ws + 44564480);
  u16* attn     = (u16*)(ws + 55050240);
  float* down_f = (float*)(ws + 65536000);
  float* up_f   = (float*)(ws + 65617920);
  u16* vbuf     = (u16*)(ws + 65699840);

  prep_downup<<<160, 256, 0, stream>>>(pal, qd, qu, kd, ku, vd, vu, od, ou, down_f, up_f);
  build_weff<<<25600, 256, 0, stream>>>(Wq, Wk, Wv, Wo, down_f, up_f, weff_qkv, weff_o);
  cvt_x<<<5120, 256, 0, stream>>>((const float4*)x, (ushort4*)xb);
  gemm128_qkv<<<dim3(32, 30), 256, 0, stream>>>(xb, weff_qkv, qbuf, kbuf, vbuf, 1280);
  vtrans<<<dim3(32, 20, 2), 256, 0, stream>>>(vbuf, vtb);
  flash_attn<<<dim3(32, 16), 256, 0, stream>>>(qbuf, kbuf, vtb, attn);
  gemm64_o<<<dim3(64, 10), 256, 0, stream>>>(attn, weff_o, out, bo, 1280);
}

// Round 11
// 301.761 us; speedup vs baseline: 1.0688x; 1.0688x over previous
//
#include <hip/hip_runtime.h>

typedef unsigned short u16;
typedef unsigned int u32;
typedef __attribute__((ext_vector_type(4))) float floatx4;
typedef __attribute__((ext_vector_type(8))) __bf16 bf16x8;

#define MFMA_BF16(a, b, c) __builtin_amdgcn_mfma_f32_16x16x32_bf16((a), (b), (c), 0, 0, 0)

typedef const __attribute__((address_space(1))) void* gas_ptr;
typedef __attribute__((address_space(3))) void* las_ptr;

__device__ __forceinline__ void gll16(const void* g, void* l) {
  __builtin_amdgcn_global_load_lds((gas_ptr)g, (las_ptr)l, 16, 0, 0);
}

__device__ __forceinline__ u16 f2bf(float x) {
  u32 u = __builtin_bit_cast(u32, x);
  u = (u + 0x7fffu + ((u >> 16) & 1u)) >> 16;
  return (u16)u;
}

// ---------------------------------------------------------------------------
// Kernel 1: down/up vectors from palette.
// ---------------------------------------------------------------------------
__global__ void prep_downup(const float* __restrict__ pal,
                            const float* __restrict__ qd, const float* __restrict__ qu,
                            const float* __restrict__ kd, const float* __restrict__ ku,
                            const float* __restrict__ vd, const float* __restrict__ vu,
                            const float* __restrict__ od, const float* __restrict__ ou,
                            float* __restrict__ down_f, float* __restrict__ up_f) {
  int tid = blockIdx.x * blockDim.x + threadIdx.x;
  int w = tid / 10240;
  int rem = tid - w * 10240;
  const float* dsrc = (w == 0) ? qd : (w == 1) ? kd : (w == 2) ? vd : od;
  const float* usrc = (w == 0) ? qu : (w == 1) ? ku : (w == 2) ? vu : ou;
  bool isdown = rem < 5120;
  int row = isdown ? rem : rem - 5120;
  const float* src = (isdown ? dsrc : usrc) + row * 15;
  float s = 0.f;
#pragma unroll
  for (int p = 0; p < 15; ++p) s += pal[p] * src[p];
  if (isdown) down_f[w * 5120 + row] = s;
  else        up_f[w * 5120 + row] = s;
}

// ---------------------------------------------------------------------------
// Kernel 2: W_eff[n][k] = W[n][k] + sum_r up[n][r]*down[r][k], cast to bf16.
// ---------------------------------------------------------------------------
__global__ void build_weff(const float* __restrict__ Wq, const float* __restrict__ Wk,
                           const float* __restrict__ Wv, const float* __restrict__ Wo,
                           const float* __restrict__ down_f, const float* __restrict__ up_f,
                           u16* __restrict__ weff_qkv, u16* __restrict__ weff_o) {
  int tid = blockIdx.x * blockDim.x + threadIdx.x;  // 4 * 1638400
  int w = tid / 1638400;
  int rem = tid - w * 1638400;
  int n = rem / 1280;
  int k = rem - n * 1280;
  const float* W = (w == 0) ? Wq : (w == 1) ? Wk : (w == 2) ? Wv : Wo;
  const float* up = up_f + w * 5120 + n * 4;
  const float* dn = down_f + w * 5120 + k;
  float v = W[rem] + up[0] * dn[0] + up[1] * dn[1280] + up[2] * dn[2560] + up[3] * dn[3840];
  u16 hv = f2bf(v);
  if (w < 3) weff_qkv[w * 1638400 + rem] = hv;
  else       weff_o[rem] = hv;
}

// ---------------------------------------------------------------------------
// Kernel 3: x fp32 -> bf16
// ---------------------------------------------------------------------------
__global__ void cvt_x(const float4* __restrict__ x, ushort4* __restrict__ xb) {
  int i = blockIdx.x * blockDim.x + threadIdx.x;  // 1310720
  float4 v = x[i];
  ushort4 o;
  o.x = f2bf(v.x); o.y = f2bf(v.y); o.z = f2bf(v.z); o.w = f2bf(v.w);
  xb[i] = o;
}

// ---------------------------------------------------------------------------
// QKV GEMM: C[M,N] = A[M,K] @ B[N,K]^T.  128x128 tile, BK=64 (20 iters vs 40
// at BK=32 — halves the per-iter barrier/vmcnt(0) drains, the documented ~20%
// stall of this structure).  Staged tiles use a rotate-by-row k-chunk swizzle
// (slot pos p of row r holds global chunk (p+r)&7) making BK=64 fragment
// reads conflict-free: start bank ((kc8-row)&7)*4 spans all 32 banks, 2-way.
// LDS 32 KB.  Epilogue: q/k/v natural coalesced bf16.
// ---------------------------------------------------------------------------
__global__ __launch_bounds__(256) void gemm128_qkv(const u16* __restrict__ A, const u16* __restrict__ Bm,
                                                   u16* __restrict__ qb, u16* __restrict__ kb,
                                                   u16* __restrict__ vbuf, int K) {
  __shared__ __align__(16) u16 lA[128 * 64];
  __shared__ __align__(16) u16 lB[128 * 64];
  const int t = threadIdx.x;
  const int lane = t & 63;
  const int l15 = lane & 15, quad = lane >> 4;
  const int wid = t >> 6;
  const int wm = (wid >> 1) * 64;
  const int wn = (wid & 1) * 64;
  const int bm = blockIdx.x * 128;
  const int bn = blockIdx.y * 128;
  floatx4 acc[4][4] = {};

  // Staging slot -> global offset (slot c: row=c>>3, pos=c&7, chunk=(pos+row)&7).
  int soff[4];
#pragma unroll
  for (int i = 0; i < 4; ++i) {
    int c = t + i * 256;
    int row = c >> 3, pos = c & 7;
    soff[i] = row * K + ((pos + row) & 7) * 8;
  }
  // Fragment read offsets (tile-invariant): row r, k-chunk kc8 at pos (kc8-r)&7.
  int afo[4][2], bfo[4][2];
#pragma unroll
  for (int i = 0; i < 4; ++i) {
#pragma unroll
    for (int ch = 0; ch < 2; ++ch) {
      int ra = wm + i * 16 + l15;
      int rb = wn + i * 16 + l15;
      int kc8 = ch * 4 + quad;
      afo[i][ch] = ra * 64 + ((kc8 - ra) & 7) * 8;
      bfo[i][ch] = rb * 64 + ((kc8 - rb) & 7) * 8;
    }
  }

  const u16* Ab = A + (long)bm * K;
  const u16* Bb = Bm + (long)bn * K;
  const int nkt = K >> 6;

  for (int kt = 0; kt < nkt; ++kt) {
    __syncthreads();
    const int k0 = kt * 64;
#pragma unroll
    for (int i = 0; i < 4; ++i) gll16(Ab + (long)soff[i] + k0, lA + (t + i * 256) * 8);
#pragma unroll
    for (int i = 0; i < 4; ++i) gll16(Bb + (long)soff[i] + k0, lB + (t + i * 256) * 8);
    __syncthreads();
#pragma unroll
    for (int ch = 0; ch < 2; ++ch) {
      bf16x8 af[4], bfr[4];
#pragma unroll
      for (int i = 0; i < 4; ++i) af[i] = *(const bf16x8*)(lA + afo[i][ch]);
#pragma unroll
      for (int i = 0; i < 4; ++i) bfr[i] = *(const bf16x8*)(lB + bfo[i][ch]);
#pragma unroll
      for (int i = 0; i < 4; ++i)
#pragma unroll
        for (int j = 0; j < 4; ++j)
          acc[i][j] = MFMA_BF16(af[i], bfr[j], acc[i][j]);
    }
  }

#pragma unroll
  for (int i = 0; i < 4; ++i) {
#pragma unroll
    for (int j = 0; j < 4; ++j) {
#pragma unroll
      for (int r = 0; r < 4; ++r) {
        int m = bm + wm + i * 16 + quad * 4 + r;
        int n = bn + wn + j * 16 + l15;
        u16 hv = f2bf(acc[i][j][r]);
        if (n < 1280) {
          qb[(long)m * 1280 + n] = hv;
        } else if (n < 2560) {
          kb[(long)m * 1280 + (n - 1280)] = hv;
        } else {
          vbuf[(long)m * 1280 + (n - 2560)] = hv;  // natural, coalesced
        }
      }
    }
  }
}

// ---------------------------------------------------------------------------
// V transpose (scalar, verified R10): vbuf[(b*2048+s)][n] ->
// vtb[(b*1280+n)*2048 + s].  64x64 tiles, tile stride 65.
// ---------------------------------------------------------------------------
__global__ __launch_bounds__(256) void vtrans(const u16* __restrict__ vbuf,
                                              u16* __restrict__ vtb) {
  __shared__ u16 tile[64 * 65];
  const int t = threadIdx.x;
  const int sb = blockIdx.x * 64, nb = blockIdx.y * 64, b = blockIdx.z;
  const u16* src = vbuf + ((long)(b * 2048 + sb)) * 1280 + nb;
#pragma unroll
  for (int it = 0; it < 16; ++it) {
    int idx = t + it * 256;
    int s = idx >> 6, n = idx & 63;
    tile[s * 65 + n] = src[(long)s * 1280 + n];
  }
  __syncthreads();
  u16* dst = vtb + ((long)(b * 1280 + nb)) * 2048 + sb;
#pragma unroll
  for (int it = 0; it < 16; ++it) {
    int idx = t + it * 256;
    int n = idx >> 6, s = idx & 63;
    dst[(long)n * 2048 + s] = tile[s * 65 + n];
  }
}

// ---------------------------------------------------------------------------
// O-proj GEMM: 64x128 tile, BK=64 (20 iters), swizzled staging as above.
// LDS 24 KB.  fp32 out + bias.
// ---------------------------------------------------------------------------
__global__ __launch_bounds__(256) void gemm64_o(const u16* __restrict__ A, const u16* __restrict__ Bm,
                                                float* __restrict__ outf,
                                                const float* __restrict__ bias, int K) {
  __shared__ __align__(16) u16 lA[64 * 64];
  __shared__ __align__(16) u16 lB[128 * 64];
  const int t = threadIdx.x;
  const int lane = t & 63;
  const int l15 = lane & 15, quad = lane >> 4;
  const int wid = t >> 6;
  const int bm = blockIdx.x * 64;
  const int bn = blockIdx.y * 128;
  floatx4 acc[4][2] = {};

  int aoff[2], boff[4];
#pragma unroll
  for (int i = 0; i < 2; ++i) {
    int c = t + i * 256;
    int row = c >> 3, pos = c & 7;
    aoff[i] = row * K + ((pos + row) & 7) * 8;
  }
#pragma unroll
  for (int i = 0; i < 4; ++i) {
    int c = t + i * 256;
    int row = c >> 3, pos = c & 7;
    boff[i] = row * K + ((pos + row) & 7) * 8;
  }
  int afo[4][2], bfo[2][2];
#pragma unroll
  for (int ch = 0; ch < 2; ++ch) {
    int kc8 = ch * 4 + quad;
#pragma unroll
    for (int i = 0; i < 4; ++i) {
      int ra = i * 16 + l15;
      afo[i][ch] = ra * 64 + ((kc8 - ra) & 7) * 8;
    }
#pragma unroll
    for (int j = 0; j < 2; ++j) {
      int rb = wid * 32 + j * 16 + l15;
      bfo[j][ch] = rb * 64 + ((kc8 - rb) & 7) * 8;
    }
  }

  const u16* Ab = A + (long)bm * K;
  const u16* Bb = Bm + (long)bn * K;
  const int nkt = K >> 6;

  for (int kt = 0; kt < nkt; ++kt) {
    __syncthreads();
    const int k0 = kt * 64;
#pragma unroll
    for (int i = 0; i < 2; ++i) gll16(Ab + (long)aoff[i] + k0, lA + (t + i * 256) * 8);
#pragma unroll
    for (int i = 0; i < 4; ++i) gll16(Bb + (long)boff[i] + k0, lB + (t + i * 256) * 8);
    __syncthreads();
#pragma unroll
    for (int ch = 0; ch < 2; ++ch) {
      bf16x8 af[4], bfr[2];
#pragma unroll
      for (int i = 0; i < 4; ++i) af[i] = *(const bf16x8*)(lA + afo[i][ch]);
#pragma unroll
      for (int j = 0; j < 2; ++j) bfr[j] = *(const bf16x8*)(lB + bfo[j][ch]);
#pragma unroll
      for (int i = 0; i < 4; ++i)
#pragma unroll
        for (int j = 0; j < 2; ++j)
          acc[i][j] = MFMA_BF16(af[i], bfr[j], acc[i][j]);
    }
  }

#pragma unroll
  for (int i = 0; i < 4; ++i) {
#pragma unroll
    for (int j = 0; j < 2; ++j) {
#pragma unroll
      for (int r = 0; r < 4; ++r) {
        int m = bm + i * 16 + quad * 4 + r;
        int n = bn + wid * 32 + j * 16 + l15;
        outf[(long)m * 1280 + n] = acc[i][j][r] + bias[n];
      }
    }
  }
}

// ---------------------------------------------------------------------------
// Flash attention v3 (best measured: ~101 µs) — unchanged.
// ---------------------------------------------------------------------------
__global__ __launch_bounds__(256) void flash_attn(const u16* __restrict__ qb,
                                                  const u16* __restrict__ kb,
                                                  const u16* __restrict__ vtb,
                                                  u16* __restrict__ attn) {
  const int S = 2048, D = 1280, HD = 160;
  __shared__ __align__(16) u16 kt_lds[64 * 160];
  __shared__ __align__(16) u16 vt_lds[160 * 64];
  __shared__ __align__(16) u16 p_lds[4][16 * 76];
  const int t = threadIdx.x, lane = t & 63, wid = t >> 6;
  const int quad = lane >> 4, l15 = lane & 15;
  const int bh = blockIdx.y, b = bh >> 3, h = bh & 7;
  const int q0 = blockIdx.x * 64 + wid * 16;
  const float kS = 0.11404582025f;

  bf16x8 aq[5];
  {
    const u16* qg = qb + ((long)(b * 2048 + q0 + l15)) * D + h * HD + quad * 8;
#pragma unroll
    for (int dc = 0; dc < 5; ++dc) aq[dc] = *(const bf16x8*)(qg + dc * 32);
  }

  const u16* kg[5];
  const u16* vg[5];
  {
    const u16* kgbase = kb + ((long)(b * 2048)) * D + h * HD;
    const u16* vgbase = vtb + ((long)(b * 1280 + h * HD)) * 2048;
#pragma unroll
    for (int i = 0; i < 5; ++i) {
      int c = t + i * 256;
      int key = c / 20, rot = c - key * 20;
      int ccol = rot - (key % 20);
      if (ccol < 0) ccol += 20;
      kg[i] = kgbase + (long)key * D + ccol * 8;
      int vrow = c >> 3, swz = c & 7;
      int vcol = swz ^ (vrow & 7);
      vg[i] = vgbase + (long)vrow * 2048 + vcol * 8;
    }
  }

  int kfo[4][5];
#pragma unroll
  for (int j = 0; j < 4; ++j) {
    int key = j * 16 + l15;
    int r0 = (quad + key) % 20;
#pragma unroll
    for (int dc = 0; dc < 5; ++dc) {
      int rot = r0 + dc * 4;
      if (rot >= 20) rot -= 20;
      kfo[j][dc] = (key * 20 + rot) * 8;
    }
  }
  int vfo[10][2];
#pragma unroll
  for (int dc = 0; dc < 10; ++dc) {
    int row = dc * 16 + l15;
#pragma unroll
    for (int ks = 0; ks < 2; ++ks) {
      int sw = (ks * 4 + quad) ^ (row & 7);
      vfo[dc][ks] = (row * 8 + sw) * 8;
    }
  }

  float l_part[4] = {0.f, 0.f, 0.f, 0.f};
  floatx4 o_acc[10] = {};

  for (int kt0 = 0; kt0 < S; kt0 += 64) {
    __syncthreads();
#pragma unroll
    for (int i = 0; i < 5; ++i) gll16(kg[i], kt_lds + (t + i * 256) * 8);
#pragma unroll
    for (int i = 0; i < 5; ++i) gll16(vg[i], vt_lds + (t + i * 256) * 8);
#pragma unroll
    for (int i = 0; i < 5; ++i) { kg[i] += (long)64 * D; vg[i] += 64; }
    __syncthreads();

    floatx4 s[4] = {};
#pragma unroll
    for (int dc = 0; dc < 5; ++dc) {
#pragma unroll
      for (int j = 0; j < 4; ++j) {
        bf16x8 kf = *(const bf16x8*)(kt_lds + kfo[j][dc]);
        s[j] = MFMA_BF16(aq[dc], kf, s[j]);
      }
    }

#pragma unroll
    for (int r = 0; r < 4; ++r) {
      float p0 = __builtin_exp2f(fminf(s[0][r] * kS, 80.f));
      float p1 = __builtin_exp2f(fminf(s[1][r] * kS, 80.f));
      float p2 = __builtin_exp2f(fminf(s[2][r] * kS, 80.f));
      float p3 = __builtin_exp2f(fminf(s[3][r] * kS, 80.f));
      l_part[r] += (p0 + p1) + (p2 + p3);
      u16* pw = p_lds[wid] + (quad * 4 + r) * 76 + l15;
      pw[0]  = f2bf(p0);
      pw[16] = f2bf(p1);
      pw[32] = f2bf(p2);
      pw[48] = f2bf(p3);
    }
    asm volatile("s_waitcnt lgkmcnt(0)" ::: "memory");

    bf16x8 paA = *(const bf16x8*)(p_lds[wid] + l15 * 76 + quad * 8);
    bf16x8 paB = *(const bf16x8*)(p_lds[wid] + l15 * 76 + 32 + quad * 8);
#pragma unroll
    for (int dc = 0; dc < 10; ++dc) {
      bf16x8 vfA = *(const bf16x8*)(vt_lds + vfo[dc][0]);
      bf16x8 vfB = *(const bf16x8*)(vt_lds + vfo[dc][1]);
      o_acc[dc] = MFMA_BF16(paA, vfA, o_acc[dc]);
      o_acc[dc] = MFMA_BF16(paB, vfB, o_acc[dc]);
    }
  }

  float rl[4];
#pragma unroll
  for (int r = 0; r < 4; ++r) {
    float rs = l_part[r];
    rs += __shfl_xor(rs, 1, 64);
    rs += __shfl_xor(rs, 2, 64);
    rs += __shfl_xor(rs, 4, 64);
    rs += __shfl_xor(rs, 8, 64);
    rl[r] = 1.0f / rs;
  }
#pragma unroll
  for (int dc = 0; dc < 10; ++dc) {
#pragma unroll
    for (int r = 0; r < 4; ++r) {
      float v = o_acc[dc][r] * rl[r];
      int row = q0 + quad * 4 + r;
      int col = h * HD + dc * 16 + l15;
      attn[((long)(b * 2048 + row)) * D + col] = f2bf(v);
    }
  }
}

// ---------------------------------------------------------------------------
// Launcher.  Workspace (~76.2 MB):
//   xb @0 | weff_qkv @10485760 | weff_o @20316160 | qbuf @23592960
//   kbuf @34078720 | vtb @44564480 | attn @55050240 | down_f @65536000
//   up_f @65617920 | vbuf @65699840 (10485760)
// ---------------------------------------------------------------------------
extern "C" void kernel_launch(void* const* d_in, const int* in_sizes, int n_in,
                              void* d_out, int out_size, void* d_ws, size_t ws_size,
                              hipStream_t stream) {
  const float* x   = (const float*)d_in[0];
  const float* pal = (const float*)d_in[1];
  const float* Wq  = (const float*)d_in[2];
  const float* Wk  = (const float*)d_in[3];
  const float* Wv  = (const float*)d_in[4];
  const float* Wo  = (const float*)d_in[5];
  const float* bo  = (const float*)d_in[6];
  const float* qd  = (const float*)d_in[7];
  const float* qu  = (const float*)d_in[8];
  const float* kd  = (const float*)d_in[9];
  const float* ku  = (const float*)d_in[10];
  const float* vd  = (const float*)d_in[11];
  const float* vu  = (const float*)d_in[12];
  const float* od  = (const float*)d_in[13];
  const float* ou  = (const float*)d_in[14];
  float* out = (float*)d_out;

  char* ws = (char*)d_ws;
  u16* xb       = (u16*)(ws);
  u16* weff_qkv = (u16*)(ws + 10485760);
  u16* weff_o   = (u16*)(ws + 20316160);
  u16* qbuf     = (u16*)(ws + 23592960);
  u16* kbuf     = (u16*)(ws + 34078720);
  u16* vtb      = (u16*)(ws + 44564480);
  u16* attn     = (u16*)(ws + 55050240);
  float* down_f = (float*)(ws + 65536000);
  float* up_f   = (float*)(ws + 65617920);
  u16* vbuf     = (u16*)(ws + 65699840);

  prep_downup<<<160, 256, 0, stream>>>(pal, qd, qu, kd, ku, vd, vu, od, ou, down_f, up_f);
  build_weff<<<25600, 256, 0, stream>>>(Wq, Wk, Wv, Wo, down_f, up_f, weff_qkv, weff_o);
  cvt_x<<<5120, 256, 0, stream>>>((const float4*)x, (ushort4*)xb);
  gemm128_qkv<<<dim3(32, 30), 256, 0, stream>>>(xb, weff_qkv, qbuf, kbuf, vbuf, 1280);
  vtrans<<<dim3(32, 20, 2), 256, 0, stream>>>(vbuf, vtb);
  flash_attn<<<dim3(32, 16), 256, 0, stream>>>(qbuf, kbuf, vtb, attn);
  gemm64_o<<<dim3(64, 10), 256, 0, stream>>>(attn, weff_o, out, bo, 1280);
}